// Round 6
// baseline (6379.826 us; speedup 1.0000x reference)
//
#include <hip/hip_runtime.h>
#include <hip/hip_bf16.h>
#include <math.h>

#define TT 1024
#define BB 256
#define LOG2PI 1.8378770664093453f

typedef short short8 __attribute__((ext_vector_type(8)));
typedef float f32x4  __attribute__((ext_vector_type(4)));

__device__ __forceinline__ float sigmoid_f(float x) {
    return 1.f / (1.f + __expf(-x));
}
__device__ __forceinline__ float tanh_f(float x) {
    return 1.f - 2.f / (__expf(2.f*x) + 1.f);
}
__device__ __forceinline__ unsigned short f2bf(float x) {   // RNE fp32->bf16
    unsigned int u = __float_as_uint(x);
    unsigned int r = (u + 0x7FFFu + ((u >> 16) & 1u)) >> 16;
    return (unsigned short)r;
}

// ---------------------------------------------------------------------------
// G[row][c] = X[row,:] . W[c,:] + bias1[c] + bias2[c]
// W is (512, K) row-major. 64-row x 64-col tile per 256-thread block.
// ---------------------------------------------------------------------------
template<int K, bool CONCAT>
__global__ __launch_bounds__(256) void gemm_ih_kernel(
    const float* __restrict__ Xa, const float* __restrict__ Xb,
    const float* __restrict__ W,
    const float* __restrict__ bias1, const float* __restrict__ bias2,
    float* __restrict__ Gout)
{
    __shared__ __align__(16) float Ws[64*68];
    __shared__ __align__(16) float Xs[64*68];
    const int tid   = threadIdx.x;
    const int chunk = blockIdx.x & 7;
    const int rtile = blockIdx.x >> 3;
    const int row0  = rtile * 64;
    const int c0    = chunk * 64;
    const int cgrp  = tid & 15;
    const int rgrp  = tid >> 4;

    float acc[4][4] = {};

    if constexpr (CONCAT) {
        for (int e = tid; e < 64*65; e += 256) {
            int c = e / 65, kk = e - c*65;
            Ws[c*68 + kk] = W[(size_t)(c0 + c)*65 + kk];
        }
        for (int e = tid; e < 64*65; e += 256) {
            int r = e / 65, kk = e - r*65;
            Xs[r*68 + kk] = (kk < 64) ? Xa[(size_t)(row0 + r)*64 + kk]
                                      : Xb[row0 + r];
        }
        __syncthreads();
        #pragma unroll 4
        for (int kq = 0; kq < 16; ++kq) {
            const int kk = kq*4;
            float4 xv[4], wv[4];
            #pragma unroll
            for (int rr = 0; rr < 4; ++rr)
                xv[rr] = *(const float4*)&Xs[(rgrp*4 + rr)*68 + kk];
            #pragma unroll
            for (int i = 0; i < 4; ++i)
                wv[i] = *(const float4*)&Ws[(cgrp + 16*i)*68 + kk];
            #pragma unroll
            for (int rr = 0; rr < 4; ++rr)
                #pragma unroll
                for (int i = 0; i < 4; ++i) {
                    float s = acc[rr][i];
                    s = fmaf(xv[rr].x, wv[i].x, s);
                    s = fmaf(xv[rr].y, wv[i].y, s);
                    s = fmaf(xv[rr].z, wv[i].z, s);
                    s = fmaf(xv[rr].w, wv[i].w, s);
                    acc[rr][i] = s;
                }
        }
        {
            float xv[4], wv[4];
            #pragma unroll
            for (int rr = 0; rr < 4; ++rr) xv[rr] = Xs[(rgrp*4 + rr)*68 + 64];
            #pragma unroll
            for (int i = 0; i < 4; ++i)  wv[i]  = Ws[(cgrp + 16*i)*68 + 64];
            #pragma unroll
            for (int rr = 0; rr < 4; ++rr)
                #pragma unroll
                for (int i = 0; i < 4; ++i)
                    acc[rr][i] = fmaf(xv[rr], wv[i], acc[rr][i]);
        }
    } else {
        for (int k0 = 0; k0 < K; k0 += 64) {
            for (int e = tid; e < 64*16; e += 256) {
                int c = e >> 4, q = e & 15;
                *(float4*)&Ws[c*68 + q*4] =
                    *(const float4*)&W[(size_t)(c0 + c)*K + k0 + q*4];
            }
            for (int e = tid; e < 64*16; e += 256) {
                int r = e >> 4, q = e & 15;
                *(float4*)&Xs[r*68 + q*4] =
                    *(const float4*)&Xa[(size_t)(row0 + r)*K + k0 + q*4];
            }
            __syncthreads();
            #pragma unroll 4
            for (int kq = 0; kq < 16; ++kq) {
                const int kk = kq*4;
                float4 xv[4], wv[4];
                #pragma unroll
                for (int rr = 0; rr < 4; ++rr)
                    xv[rr] = *(const float4*)&Xs[(rgrp*4 + rr)*68 + kk];
                #pragma unroll
                for (int i = 0; i < 4; ++i)
                    wv[i] = *(const float4*)&Ws[(cgrp + 16*i)*68 + kk];
                #pragma unroll
                for (int rr = 0; rr < 4; ++rr)
                    #pragma unroll
                    for (int i = 0; i < 4; ++i) {
                        float s = acc[rr][i];
                        s = fmaf(xv[rr].x, wv[i].x, s);
                        s = fmaf(xv[rr].y, wv[i].y, s);
                        s = fmaf(xv[rr].z, wv[i].z, s);
                        s = fmaf(xv[rr].w, wv[i].w, s);
                        acc[rr][i] = s;
                    }
            }
            __syncthreads();
        }
    }

    #pragma unroll
    for (int i = 0; i < 4; ++i) {
        const int c = c0 + cgrp + 16*i;
        const float bb = bias1[c] + bias2[c];
        #pragma unroll
        for (int rr = 0; rr < 4; ++rr) {
            const int r = row0 + rgrp*4 + rr;
            Gout[(size_t)r*512 + c] = acc[rr][i] + bb;
        }
    }
}

// ---------------------------------------------------------------------------
// MFMA-based sequential LSTM pass. 4 batch elements per block (M=4 in a
// 16x16x32 bf16 MFMA tile; rows 4-15 are don't-care). 512 threads = 8 waves;
// wave w owns gate columns [w*64, w*64+64) = 4 N-tiles x 4 K-slices ->
// 16 MFMA/step, weights as 64 VGPRs of bf16 B-fragments (loaded once).
// h kept in LDS as bf16 (A-frags = 4 ds_read_b128/wave/step). G row block
// (4x512 fp32) prefetched one step ahead, staged via LDS.
// Phases per step: [stageG + MFMA] bar [gate nonlin (lanes 0-15)] bar
// [c/h update by (r,m)-threads] bar.  Only matvec inputs are bf16; G, acc,
// c, nonlinearities all fp32.
// ---------------------------------------------------------------------------
__global__ __launch_bounds__(512, 2) void lstm_mfma_kernel(
    const float* __restrict__ G,       // (steps*BB, 512) chunk-local, incl. biases
    const float* __restrict__ wh,      // (512,128)
    float* __restrict__ h_state,       // (BB,128) in/out (layer slice)
    float* __restrict__ c_state,       // (BB,128) in/out
    float* __restrict__ h_all,         // (steps*BB,128) chunk-local
    int steps)
{
    const int tid  = threadIdx.x;
    const int wave = tid >> 6;          // 0..7
    const int lane = tid & 63;
    const int b0   = blockIdx.x * 4;    // 4 batch rows per block

    __shared__ float G_lds[4*512];
    __shared__ float nl_lds[4*512];
    __shared__ __align__(16) unsigned short h_bf[4*136];   // bf16 h, padded rows

    // --- B fragments: B[k][n] = Whh[n][k], bf16. lane: col=lane&15, k=(lane>>4)*8+i
    short8 bfrag[4][4];   // [tile][kslice]
    {
        const int coln = lane & 15, kg = lane >> 4;
        #pragma unroll
        for (int tn = 0; tn < 4; ++tn) {
            const int j = wave*64 + tn*16 + coln;          // gate row of wh
            #pragma unroll
            for (int ks = 0; ks < 4; ++ks) {
                const float* src = wh + (size_t)j*128 + ks*32 + kg*8;
                short8 v;
                #pragma unroll
                for (int i = 0; i < 8; ++i) v[i] = (short)f2bf(src[i]);
                bfrag[tn][ks] = v;
            }
        }
    }

    // --- state init: thread owns (r_own = tid>>7, m_own = tid&127)
    const int r_own = tid >> 7;
    const int m_own = tid & 127;
    float c_reg, hv_last;
    {
        hv_last = h_state[(b0 + r_own)*128 + m_own];
        c_reg   = c_state[(b0 + r_own)*128 + m_own];
        h_bf[r_own*136 + m_own] = f2bf(hv_last);
    }
    // preload G row block for t=0 (4 rows x 512 = one float4 per thread)
    f32x4 gstage;
    gstage = *(const f32x4*)(G + ((size_t)b0 + r_own)*512 + m_own*4);
    __syncthreads();

    for (int t = 0; t < steps; ++t) {
        // stage G(t) -> LDS; issue load of G(t+1)
        *(f32x4*)&G_lds[r_own*512 + m_own*4] = gstage;
        if (t + 1 < steps)
            gstage = *(const f32x4*)(G + ((size_t)(t+1)*BB + b0 + r_own)*512 + m_own*4);

        // A fragments from h_bf: lane row = lane&3 (real rows 0-3; rows 4-15 don't-care)
        short8 af[4];
        {
            const int rr = lane & 3, kg = lane >> 4;
            #pragma unroll
            for (int ks = 0; ks < 4; ++ks)
                af[ks] = *(const short8*)&h_bf[rr*136 + ks*32 + kg*8];
        }
        f32x4 acc[4];
        #pragma unroll
        for (int tn = 0; tn < 4; ++tn) {
            f32x4 a = {0.f, 0.f, 0.f, 0.f};
            #pragma unroll
            for (int ks = 0; ks < 4; ++ks)
                a = __builtin_amdgcn_mfma_f32_16x16x32_bf16(af[ks], bfrag[tn][ks], a, 0, 0, 0);
            acc[tn] = a;
        }
        __syncthreads();   // G_lds visible; acc ready

        // gate nonlinearity: lanes 0-15 hold rows 0-3 in acc regs 0-3
        if (lane < 16) {
            const bool istanh = ((wave >> 1) == 2);        // waves 4,5 = g-gate
            #pragma unroll
            for (int tn = 0; tn < 4; ++tn) {
                const int j = wave*64 + tn*16 + lane;
                #pragma unroll
                for (int rg = 0; rg < 4; ++rg) {
                    float s = acc[tn][rg] + G_lds[rg*512 + j];
                    float e = __expf(istanh ? 2.f*s : -s);
                    nl_lds[rg*512 + j] = istanh ? (1.f - 2.f/(e + 1.f))
                                                : 1.f/(1.f + e);
                }
            }
        }
        __syncthreads();

        // c/h update: one (r,m) per thread
        {
            float iv = nl_lds[r_own*512 +        m_own];
            float fv = nl_lds[r_own*512 + 128 + m_own];
            float gv = nl_lds[r_own*512 + 256 + m_own];
            float ov = nl_lds[r_own*512 + 384 + m_own];
            c_reg = fmaf(fv, c_reg, iv*gv);
            float hv = ov * tanh_f(c_reg);
            hv_last = hv;
            h_bf[r_own*136 + m_own] = f2bf(hv);
            h_all[((size_t)t*BB + b0 + r_own)*128 + m_own] = hv;
        }
        __syncthreads();
    }
    h_state[(b0 + r_own)*128 + m_own] = hv_last;
    c_state[(b0 + r_own)*128 + m_own] = c_reg;
}

// ---------------------------------------------------------------------------
__global__ __launch_bounds__(256) void init_state_kernel(
    const float* __restrict__ h0, const float* __restrict__ c0,
    float* __restrict__ h_state, float* __restrict__ c_state)
{
    const int idx = blockIdx.x*256 + threadIdx.x;
    h_state[idx] = h0[idx];
    c_state[idx] = c0[idx];
}

// ---------------------------------------------------------------------------
// Goal decoder: latents(64) -> 64 relu -> 32 ; goals + log_prob_goals
// ---------------------------------------------------------------------------
__global__ __launch_bounds__(256) void dec_goal_kernel(
    const float* __restrict__ h2,
    const float* __restrict__ geps,
    const float* __restrict__ w1, const float* __restrict__ b1,
    const float* __restrict__ w2, const float* __restrict__ b2,
    float* __restrict__ out_goals, float* __restrict__ out_lpg)
{
    __shared__ float W1[64*64];
    __shared__ float W2[32*64];
    __shared__ float B1[64];
    __shared__ float B2[32];
    const int tid = threadIdx.x;
    for (int e = tid; e < 64*64; e += 256) W1[e] = w1[e];
    for (int e = tid; e < 32*64; e += 256) W2[e] = w2[e];
    if (tid < 64) B1[tid] = b1[tid];
    if (tid < 32) B2[tid] = b2[tid];
    __syncthreads();

    const size_t row = (size_t)blockIdx.x*256 + tid;
    const float* xr = h2 + row*128;

    float hid[64];
    #pragma unroll
    for (int jj = 0; jj < 64; ++jj) hid[jj] = B1[jj];
    for (int k = 0; k < 64; k += 4) {
        float4 xv = *(const float4*)(xr + k);
        #pragma unroll
        for (int jj = 0; jj < 64; ++jj) {
            float s = hid[jj];
            s = fmaf(W1[jj*64 + k],     xv.x, s);
            s = fmaf(W1[jj*64 + k + 1], xv.y, s);
            s = fmaf(W1[jj*64 + k + 2], xv.z, s);
            s = fmaf(W1[jj*64 + k + 3], xv.w, s);
            hid[jj] = s;
        }
    }
    #pragma unroll
    for (int jj = 0; jj < 64; ++jj) hid[jj] = fmaxf(hid[jj], 0.f);

    float gm[16];
    #pragma unroll
    for (int jj = 0; jj < 16; ++jj) {
        float s = B2[jj];
        #pragma unroll
        for (int k = 0; k < 64; ++k) s = fmaf(W2[jj*64 + k], hid[k], s);
        gm[jj] = 100.f * tanh_f(0.001f * s);
    }
    float ge[16];
    #pragma unroll
    for (int d = 0; d < 16; d += 4) {
        float4 v = *(const float4*)(geps + row*16 + d);
        ge[d]=v.x; ge[d+1]=v.y; ge[d+2]=v.z; ge[d+3]=v.w;
    }
    float lsum = 0.f;
    float goalv[16];
    #pragma unroll
    for (int jj = 0; jj < 16; ++jj) {
        float s = B2[16 + jj];
        #pragma unroll
        for (int k = 0; k < 64; ++k) s = fmaf(W2[(16+jj)*64 + k], hid[k], s);
        float gs   = tanh_f(s);
        float gvar = fmaf(gs, gs, 0.001f);
        float goal = fmaf(sqrtf(gvar), ge[jj], gm[jj]);
        goalv[jj] = goal;
        float dd = goal - gm[jj];
        lsum += dd*dd/gvar + __logf(gvar);
    }
    #pragma unroll
    for (int d = 0; d < 16; d += 4) {
        float4 v = make_float4(goalv[d], goalv[d+1], goalv[d+2], goalv[d+3]);
        *(float4*)(out_goals + row*16 + d) = v;
    }
    out_lpg[row] = -0.5f*(lsum + 16.f*LOG2PI);
}

// ---------------------------------------------------------------------------
// Action + value decoder: goal_obs(80) -> [ad: 80 relu -> 16], [vd: 80 relu -> 1]
// ---------------------------------------------------------------------------
__global__ __launch_bounds__(256) void dec_av_kernel(
    const float* __restrict__ goals,
    const float* __restrict__ obs,
    const float* __restrict__ aeps,
    const float* __restrict__ aw1, const float* __restrict__ ab1,
    const float* __restrict__ aw2, const float* __restrict__ ab2,
    const float* __restrict__ vw1, const float* __restrict__ vb1,
    const float* __restrict__ vw2, const float* __restrict__ vb2,
    float* __restrict__ out_actions, float* __restrict__ out_lpa,
    float* __restrict__ out_values)
{
    __shared__ float AW1[80*80];
    __shared__ float VW1[80*80];
    __shared__ float AW2[16*80];
    __shared__ float VW2[80];
    __shared__ float AB1[80];
    __shared__ float VB1[80];
    __shared__ float AB2[16];
    const int tid = threadIdx.x;
    for (int e = tid; e < 80*80; e += 256) { AW1[e] = aw1[e]; VW1[e] = vw1[e]; }
    for (int e = tid; e < 16*80; e += 256) AW2[e] = aw2[e];
    if (tid < 80) { VW2[tid] = vw2[tid]; AB1[tid] = ab1[tid]; VB1[tid] = vb1[tid]; }
    if (tid < 16) AB2[tid] = ab2[tid];
    __syncthreads();

    const size_t row = (size_t)blockIdx.x*256 + tid;

    float hid[80];
    #pragma unroll
    for (int jj = 0; jj < 80; ++jj) hid[jj] = AB1[jj];
    for (int k = 0; k < 80; k += 4) {
        float4 xv;
        if (k < 16) xv = *(const float4*)(goals + row*16 + k);
        else        xv = *(const float4*)(obs + row*64 + (k - 16));
        #pragma unroll
        for (int jj = 0; jj < 80; ++jj) {
            float s = hid[jj];
            s = fmaf(AW1[jj*80 + k],     xv.x, s);
            s = fmaf(AW1[jj*80 + k + 1], xv.y, s);
            s = fmaf(AW1[jj*80 + k + 2], xv.z, s);
            s = fmaf(AW1[jj*80 + k + 3], xv.w, s);
            hid[jj] = s;
        }
    }
    #pragma unroll
    for (int jj = 0; jj < 80; ++jj) hid[jj] = fmaxf(hid[jj], 0.f);

    float am[8], asd[8];
    #pragma unroll
    for (int jj = 0; jj < 8; ++jj) {
        float s = AB2[jj];
        #pragma unroll
        for (int k = 0; k < 80; ++k) s = fmaf(AW2[jj*80 + k], hid[k], s);
        am[jj] = s;
    }
    #pragma unroll
    for (int jj = 0; jj < 8; ++jj) {
        float s = AB2[8 + jj];
        #pragma unroll
        for (int k = 0; k < 80; ++k) s = fmaf(AW2[(8+jj)*80 + k], hid[k], s);
        asd[jj] = s;
    }

    float ae[8];
    #pragma unroll
    for (int d = 0; d < 8; d += 4) {
        float4 v = *(const float4*)(aeps + row*8 + d);
        ae[d]=v.x; ae[d+1]=v.y; ae[d+2]=v.z; ae[d+3]=v.w;
    }
    float lsum = 0.f;
    float actv[8];
    #pragma unroll
    for (int d = 0; d < 8; ++d) {
        float avar = fmaf(asd[d], asd[d], 0.001f);
        float act  = fmaf(sqrtf(avar), ae[d], am[d]);
        actv[d] = act;
        float dd = act - am[d];
        lsum += dd*dd/avar + __logf(avar);
    }
    #pragma unroll
    for (int d = 0; d < 8; d += 4) {
        float4 v = make_float4(actv[d], actv[d+1], actv[d+2], actv[d+3]);
        *(float4*)(out_actions + row*8 + d) = v;
    }
    out_lpa[row] = -0.5f*(lsum + 8.f*LOG2PI);

    float vh[80];
    #pragma unroll
    for (int jj = 0; jj < 80; ++jj) vh[jj] = VB1[jj];
    for (int k = 0; k < 80; k += 4) {
        float4 xv;
        if (k < 16) xv = *(const float4*)(goals + row*16 + k);
        else        xv = *(const float4*)(obs + row*64 + (k - 16));
        #pragma unroll
        for (int jj = 0; jj < 80; ++jj) {
            float s = vh[jj];
            s = fmaf(VW1[jj*80 + k],     xv.x, s);
            s = fmaf(VW1[jj*80 + k + 1], xv.y, s);
            s = fmaf(VW1[jj*80 + k + 2], xv.z, s);
            s = fmaf(VW1[jj*80 + k + 3], xv.w, s);
            vh[jj] = s;
        }
    }
    float v = vb2[0];
    #pragma unroll
    for (int jj = 0; jj < 80; ++jj) v = fmaf(VW2[jj], fmaxf(vh[jj], 0.f), v);
    out_values[row] = v;
}

// ---------------------------------------------------------------------------
// lp decoder: full_lat_obs(192) -> 192 relu -> 1. 4 lanes per item,
// quad reduce via shfl_xor, w1 staged in LDS (float4) in 3 chunks of 64 rows.
// ---------------------------------------------------------------------------
__global__ __launch_bounds__(256) void dec_lpv_kernel(
    const float* __restrict__ h2,
    const float* __restrict__ obs,
    const float* __restrict__ w1, const float* __restrict__ b1,
    const float* __restrict__ w2, const float* __restrict__ b2,
    float* __restrict__ out_lpv)
{
    __shared__ __align__(16) float W1s[64*192];
    __shared__ float B1[192];
    __shared__ float W2[192];
    const int tid = threadIdx.x;
    const int l = tid & 3;
    const size_t item = (size_t)blockIdx.x*64 + (tid >> 2);
    if (tid < 192) { B1[tid] = b1[tid]; W2[tid] = w2[tid]; }

    float x[48];
    #pragma unroll
    for (int q = 0; q < 12; ++q) {
        int gk = l*48 + q*4;
        float4 v;
        if (gk < 128) v = *(const float4*)(h2 + item*128 + gk);
        else          v = *(const float4*)(obs + item*64 + (gk - 128));
        x[q*4]=v.x; x[q*4+1]=v.y; x[q*4+2]=v.z; x[q*4+3]=v.w;
    }

    float acc = 0.f;
    for (int j0 = 0; j0 < 192; j0 += 64) {
        __syncthreads();
        for (int e = tid; e < 64*48; e += 256) {
            int rr = e / 48, q = e - rr*48;
            *(float4*)&W1s[rr*192 + q*4] =
                *(const float4*)&w1[(size_t)(j0 + rr)*192 + q*4];
        }
        __syncthreads();
        for (int jj = 0; jj < 64; ++jj) {
            const float* wr = W1s + jj*192 + l*48;
            float p = 0.f;
            #pragma unroll
            for (int q = 0; q < 12; ++q) {
                float4 wv = *(const float4*)(wr + q*4);
                p = fmaf(wv.x, x[q*4],     p);
                p = fmaf(wv.y, x[q*4 + 1], p);
                p = fmaf(wv.z, x[q*4 + 2], p);
                p = fmaf(wv.w, x[q*4 + 3], p);
            }
            p += __shfl_xor(p, 1);
            p += __shfl_xor(p, 2);
            float h = fmaxf(p + B1[j0 + jj], 0.f);
            acc = fmaf(W2[j0 + jj], h, acc);
        }
    }
    if (l == 0) out_lpv[item] = acc + b2[0];
}

// ---------------------------------------------------------------------------
extern "C" void kernel_launch(void* const* d_in, const int* in_sizes, int n_in,
                              void* d_out, int out_size, void* d_ws, size_t ws_size,
                              hipStream_t stream)
{
    (void)in_sizes; (void)n_in; (void)out_size;

    const float* obs    = (const float*)d_in[0];
    const float* lps    = (const float*)d_in[1];
    const float* geps   = (const float*)d_in[2];
    const float* aeps   = (const float*)d_in[3];
    const float* h0     = (const float*)d_in[4];
    const float* c0     = (const float*)d_in[5];
    const float* w_ih0  = (const float*)d_in[6];
    const float* b_ih0  = (const float*)d_in[7];
    const float* w_hh0  = (const float*)d_in[8];
    const float* b_hh0  = (const float*)d_in[9];
    const float* w_ih1  = (const float*)d_in[10];
    const float* b_ih1  = (const float*)d_in[11];
    const float* w_hh1  = (const float*)d_in[12];
    const float* b_hh1  = (const float*)d_in[13];
    const float* gd_w1  = (const float*)d_in[14];
    const float* gd_b1  = (const float*)d_in[15];
    const float* gd_w2  = (const float*)d_in[16];
    const float* gd_b2  = (const float*)d_in[17];
    const float* ad_w1  = (const float*)d_in[18];
    const float* ad_b1  = (const float*)d_in[19];
    const float* ad_w2  = (const float*)d_in[20];
    const float* ad_b2  = (const float*)d_in[21];
    const float* vd_w1  = (const float*)d_in[22];
    const float* vd_b1  = (const float*)d_in[23];
    const float* vd_w2  = (const float*)d_in[24];
    const float* vd_b2  = (const float*)d_in[25];
    const float* lpd_w1 = (const float*)d_in[26];
    const float* lpd_b1 = (const float*)d_in[27];
    const float* lpd_w2 = (const float*)d_in[28];
    const float* lpd_b2 = (const float*)d_in[29];

    float* out         = (float*)d_out;
    float* out_actions = out;                 // (T,B,8)
    float* out_lpa     = out + 2097152;       // (T,B)
    float* out_goals   = out + 2359296;       // (T,B,16)
    float* out_lpg     = out + 6553600;       // (T,B)
    float* out_values  = out + 6815744;       // (T,B,1)
    float* out_lpv     = out + 7077888;       // (T,B,1)

    // --- adaptive time-chunking to fit ws_size ---
    const size_t STATE_ELEMS = 2ull * BB * 128;            // per h or c
    const size_t state_bytes = 2ull * STATE_ELEMS * 4;     // h + c
    int C = 0;
    for (int c = TT; c >= 8; c >>= 1) {
        size_t need = (size_t)c * BB * (512 + 128 + 128) * 4 + state_bytes;
        if (need <= ws_size) { C = c; break; }
    }
    if (C == 0) return;
    const int nchunks = TT / C;

    float* Gc      = (float*)d_ws;
    float* h1c     = Gc  + (size_t)C * BB * 512;
    float* h2c     = h1c + (size_t)C * BB * 128;
    float* h_state = h2c + (size_t)C * BB * 128;
    float* c_state = h_state + STATE_ELEMS;

    const dim3 blk(256);
    init_state_kernel<<<dim3((int)(STATE_ELEMS/256)), blk, 0, stream>>>(
        h0, c0, h_state, c_state);

    for (int ch = 0; ch < nchunks; ++ch) {
        const size_t crow0 = (size_t)ch * C * BB;
        const int rows = C * BB;

        gemm_ih_kernel<65, true><<<dim3((rows/64)*8), blk, 0, stream>>>(
            obs + crow0*64, lps + crow0, w_ih0, b_ih0, b_hh0, Gc);

        lstm_mfma_kernel<<<dim3(BB/4), dim3(512), 0, stream>>>(
            Gc, w_hh0, h_state, c_state, h1c, C);

        gemm_ih_kernel<128, false><<<dim3((rows/64)*8), blk, 0, stream>>>(
            h1c, nullptr, w_ih1, b_ih1, b_hh1, Gc);

        lstm_mfma_kernel<<<dim3(BB/4), dim3(512), 0, stream>>>(
            Gc, w_hh1, h_state + BB*128, c_state + BB*128, h2c, C);

        dec_goal_kernel<<<dim3(rows/256), blk, 0, stream>>>(
            h2c, geps + crow0*16, gd_w1, gd_b1, gd_w2, gd_b2,
            out_goals + crow0*16, out_lpg + crow0);

        dec_av_kernel<<<dim3(rows/256), blk, 0, stream>>>(
            out_goals + crow0*16, obs + crow0*64, aeps + crow0*8,
            ad_w1, ad_b1, ad_w2, ad_b2, vd_w1, vd_b1, vd_w2, vd_b2,
            out_actions + crow0*8, out_lpa + crow0, out_values + crow0);

        dec_lpv_kernel<<<dim3(rows/64), blk, 0, stream>>>(
            h2c, obs + crow0*64, lpd_w1, lpd_b1, lpd_w2, lpd_b2,
            out_lpv + crow0);
    }
}

// Round 7
// 3549.315 us; speedup vs baseline: 1.7975x; 1.7975x over previous
//
#include <hip/hip_runtime.h>
#include <hip/hip_bf16.h>
#include <math.h>

#define TT 1024
#define BB 256
#define LOG2PI 1.8378770664093453f

typedef short short8 __attribute__((ext_vector_type(8)));
typedef float f32x4  __attribute__((ext_vector_type(4)));

__device__ __forceinline__ float sigmoid_f(float x) {
    return 1.f / (1.f + __expf(-x));
}
__device__ __forceinline__ float tanh_f(float x) {
    return 1.f - 2.f / (__expf(2.f*x) + 1.f);
}
__device__ __forceinline__ unsigned short f2bf(float x) {   // RNE fp32->bf16
    unsigned int u = __float_as_uint(x);
    unsigned int r = (u + 0x7FFFu + ((u >> 16) & 1u)) >> 16;
    return (unsigned short)r;
}

// ---------------------------------------------------------------------------
// G[row][c] = X[row,:] . W[c,:] + bias1[c] + bias2[c]
// W is (512, K) row-major. 64-row x 64-col tile per 256-thread block.
// ---------------------------------------------------------------------------
template<int K, bool CONCAT>
__global__ __launch_bounds__(256) void gemm_ih_kernel(
    const float* __restrict__ Xa, const float* __restrict__ Xb,
    const float* __restrict__ W,
    const float* __restrict__ bias1, const float* __restrict__ bias2,
    float* __restrict__ Gout)
{
    __shared__ __align__(16) float Ws[64*68];
    __shared__ __align__(16) float Xs[64*68];
    const int tid   = threadIdx.x;
    const int chunk = blockIdx.x & 7;
    const int rtile = blockIdx.x >> 3;
    const int row0  = rtile * 64;
    const int c0    = chunk * 64;
    const int cgrp  = tid & 15;
    const int rgrp  = tid >> 4;

    float acc[4][4] = {};

    if constexpr (CONCAT) {
        for (int e = tid; e < 64*65; e += 256) {
            int c = e / 65, kk = e - c*65;
            Ws[c*68 + kk] = W[(size_t)(c0 + c)*65 + kk];
        }
        for (int e = tid; e < 64*65; e += 256) {
            int r = e / 65, kk = e - r*65;
            Xs[r*68 + kk] = (kk < 64) ? Xa[(size_t)(row0 + r)*64 + kk]
                                      : Xb[row0 + r];
        }
        __syncthreads();
        #pragma unroll 4
        for (int kq = 0; kq < 16; ++kq) {
            const int kk = kq*4;
            float4 xv[4], wv[4];
            #pragma unroll
            for (int rr = 0; rr < 4; ++rr)
                xv[rr] = *(const float4*)&Xs[(rgrp*4 + rr)*68 + kk];
            #pragma unroll
            for (int i = 0; i < 4; ++i)
                wv[i] = *(const float4*)&Ws[(cgrp + 16*i)*68 + kk];
            #pragma unroll
            for (int rr = 0; rr < 4; ++rr)
                #pragma unroll
                for (int i = 0; i < 4; ++i) {
                    float s = acc[rr][i];
                    s = fmaf(xv[rr].x, wv[i].x, s);
                    s = fmaf(xv[rr].y, wv[i].y, s);
                    s = fmaf(xv[rr].z, wv[i].z, s);
                    s = fmaf(xv[rr].w, wv[i].w, s);
                    acc[rr][i] = s;
                }
        }
        {
            float xv[4], wv[4];
            #pragma unroll
            for (int rr = 0; rr < 4; ++rr) xv[rr] = Xs[(rgrp*4 + rr)*68 + 64];
            #pragma unroll
            for (int i = 0; i < 4; ++i)  wv[i]  = Ws[(cgrp + 16*i)*68 + 64];
            #pragma unroll
            for (int rr = 0; rr < 4; ++rr)
                #pragma unroll
                for (int i = 0; i < 4; ++i)
                    acc[rr][i] = fmaf(xv[rr], wv[i], acc[rr][i]);
        }
    } else {
        for (int k0 = 0; k0 < K; k0 += 64) {
            for (int e = tid; e < 64*16; e += 256) {
                int c = e >> 4, q = e & 15;
                *(float4*)&Ws[c*68 + q*4] =
                    *(const float4*)&W[(size_t)(c0 + c)*K + k0 + q*4];
            }
            for (int e = tid; e < 64*16; e += 256) {
                int r = e >> 4, q = e & 15;
                *(float4*)&Xs[r*68 + q*4] =
                    *(const float4*)&Xa[(size_t)(row0 + r)*K + k0 + q*4];
            }
            __syncthreads();
            #pragma unroll 4
            for (int kq = 0; kq < 16; ++kq) {
                const int kk = kq*4;
                float4 xv[4], wv[4];
                #pragma unroll
                for (int rr = 0; rr < 4; ++rr)
                    xv[rr] = *(const float4*)&Xs[(rgrp*4 + rr)*68 + kk];
                #pragma unroll
                for (int i = 0; i < 4; ++i)
                    wv[i] = *(const float4*)&Ws[(cgrp + 16*i)*68 + kk];
                #pragma unroll
                for (int rr = 0; rr < 4; ++rr)
                    #pragma unroll
                    for (int i = 0; i < 4; ++i) {
                        float s = acc[rr][i];
                        s = fmaf(xv[rr].x, wv[i].x, s);
                        s = fmaf(xv[rr].y, wv[i].y, s);
                        s = fmaf(xv[rr].z, wv[i].z, s);
                        s = fmaf(xv[rr].w, wv[i].w, s);
                        acc[rr][i] = s;
                    }
            }
            __syncthreads();
        }
    }

    #pragma unroll
    for (int i = 0; i < 4; ++i) {
        const int c = c0 + cgrp + 16*i;
        const float bb = bias1[c] + bias2[c];
        #pragma unroll
        for (int rr = 0; rr < 4; ++rr) {
            const int r = row0 + rgrp*4 + rr;
            Gout[(size_t)r*512 + c] = acc[rr][i] + bb;
        }
    }
}

// ---------------------------------------------------------------------------
// MFMA sequential LSTM pass, ONE batch element per block (256 blocks = all
// CUs). 512 threads = 8 waves; wave w owns gates [w*64, w*64+64) permuted so
// tile tn, col c -> gate w*64 + c*4 + tn. Lane l<16 then holds row-0 acc for
// 4 CONTIGUOUS gates -> in-register nonlinearity + one ds_write_b128.
// Weights: 64 VGPRs bf16 B-frags (verified resident in round 6).
// h as bf16 in LDS (4 broadcast ds_read_b128/wave/step). G read per-lane
// from global as f32x4 (coalesced, no LDS staging), prefetched 2 steps ahead.
// 2 barriers/step. C/D layout (verified by round-6 pass): col=lane&15,
// row=(lane>>4)*4+reg; A row = lane&15 (uniform h -> all rows identical).
// ---------------------------------------------------------------------------
__global__ __launch_bounds__(512, 2) void lstm_mfma_kernel(
    const float* __restrict__ G,       // (steps*BB, 512) chunk-local, incl. biases
    const float* __restrict__ wh,      // (512,128)
    float* __restrict__ h_state,       // (BB,128) in/out (layer slice)
    float* __restrict__ c_state,       // (BB,128) in/out
    float* __restrict__ h_all,         // (steps*BB,128) chunk-local
    int steps)
{
    const int tid  = threadIdx.x;
    const int wave = tid >> 6;          // 0..7
    const int lane = tid & 63;
    const int b    = blockIdx.x;
    const int col  = lane & 15;
    const int kg   = lane >> 4;         // k-group 0..3

    __shared__ float nl_lds[512];
    __shared__ __align__(16) unsigned short h_bf[128];

    // B fragments: tile tn covers gate j = wave*64 + col*4 + tn
    // B[k][n]: lane supplies col (lane&15), k = ks*32 + kg*8 + i
    short8 bfrag[4][4];   // [tile][kslice]
    {
        #pragma unroll
        for (int tn = 0; tn < 4; ++tn) {
            const int j = wave*64 + col*4 + tn;
            #pragma unroll
            for (int ks = 0; ks < 4; ++ks) {
                const float* src = wh + (size_t)j*128 + ks*32 + kg*8;
                short8 v;
                #pragma unroll
                for (int i = 0; i < 8; ++i) v[i] = (short)f2bf(src[i]);
                bfrag[tn][ks] = v;
            }
        }
    }

    // state: threads 0-127 own h/c element m = tid
    float c_reg = 0.f, hv_last = 0.f;
    if (tid < 128) {
        hv_last = h_state[b*128 + tid];
        c_reg   = c_state[b*128 + tid];
        h_bf[tid] = f2bf(hv_last);
    }

    const size_t goff = (size_t)b*512 + wave*64 + col*4;
    // 2-deep G prefetch (covers ~900cyc HBM latency; each row read once/block)
    f32x4 gA = *(const f32x4*)(G + goff);                       // t = 0
    f32x4 gB = *(const f32x4*)(G + (size_t)BB*512*(steps > 1 ? 1 : 0) + goff); // t = 1
    __syncthreads();

    #define LSTM_STEP(T, GUSE, GRELOAD, TFAR)                                  \
    {                                                                          \
        const int t_ = (T);                                                    \
        short8 af[4];                                                          \
        _Pragma("unroll")                                                      \
        for (int ks = 0; ks < 4; ++ks)                                         \
            af[ks] = *(const short8*)&h_bf[ks*32 + kg*8];                      \
        f32x4 guse = (GUSE);                                                   \
        if ((TFAR) < steps)                                                    \
            (GRELOAD) = *(const f32x4*)(G + (size_t)(TFAR)*BB*512 + goff);     \
        f32x4 acc[4];                                                          \
        _Pragma("unroll")                                                      \
        for (int tn = 0; tn < 4; ++tn) {                                       \
            f32x4 a = {0.f, 0.f, 0.f, 0.f};                                    \
            _Pragma("unroll")                                                  \
            for (int ks = 0; ks < 4; ++ks)                                     \
                a = __builtin_amdgcn_mfma_f32_16x16x32_bf16(                   \
                        af[ks], bfrag[tn][ks], a, 0, 0, 0);                    \
            acc[tn] = a;                                                       \
        }                                                                      \
        if (lane < 16) {                                                       \
            const int jbase = wave*64 + col*4;                                 \
            f32x4 nlv;                                                         \
            _Pragma("unroll")                                                  \
            for (int tn = 0; tn < 4; ++tn) {                                   \
                float s = acc[tn][0] + guse[tn];                               \
                const bool istanh = (((jbase + tn) >> 7) == 2);                \
                float e = __expf(istanh ? 2.f*s : -s);                         \
                nlv[tn] = istanh ? (1.f - 2.f/(e + 1.f)) : 1.f/(1.f + e);      \
            }                                                                  \
            *(f32x4*)&nl_lds[jbase] = nlv;                                     \
        }                                                                      \
        __syncthreads();                                                       \
        if (tid < 128) {                                                       \
            float iv = nl_lds[tid];                                            \
            float fv = nl_lds[128 + tid];                                      \
            float gv = nl_lds[256 + tid];                                      \
            float ov = nl_lds[384 + tid];                                      \
            c_reg = fmaf(fv, c_reg, iv*gv);                                    \
            float hv = ov * tanh_f(c_reg);                                     \
            hv_last = hv;                                                      \
            h_bf[tid] = f2bf(hv);                                              \
            h_all[((size_t)t_*BB + b)*128 + tid] = hv;                         \
        }                                                                      \
        __syncthreads();                                                       \
    }

    for (int t = 0; t < steps; t += 2) {
        LSTM_STEP(t,     gA, gA, t + 2);
        LSTM_STEP(t + 1, gB, gB, t + 3);
    }
    #undef LSTM_STEP

    if (tid < 128) {
        h_state[b*128 + tid] = hv_last;
        c_state[b*128 + tid] = c_reg;
    }
}

// ---------------------------------------------------------------------------
__global__ __launch_bounds__(256) void init_state_kernel(
    const float* __restrict__ h0, const float* __restrict__ c0,
    float* __restrict__ h_state, float* __restrict__ c_state)
{
    const int idx = blockIdx.x*256 + threadIdx.x;
    h_state[idx] = h0[idx];
    c_state[idx] = c0[idx];
}

// ---------------------------------------------------------------------------
// Goal decoder: latents(64) -> 64 relu -> 32 ; goals + log_prob_goals
// ---------------------------------------------------------------------------
__global__ __launch_bounds__(256) void dec_goal_kernel(
    const float* __restrict__ h2,
    const float* __restrict__ geps,
    const float* __restrict__ w1, const float* __restrict__ b1,
    const float* __restrict__ w2, const float* __restrict__ b2,
    float* __restrict__ out_goals, float* __restrict__ out_lpg)
{
    __shared__ float W1[64*64];
    __shared__ float W2[32*64];
    __shared__ float B1[64];
    __shared__ float B2[32];
    const int tid = threadIdx.x;
    for (int e = tid; e < 64*64; e += 256) W1[e] = w1[e];
    for (int e = tid; e < 32*64; e += 256) W2[e] = w2[e];
    if (tid < 64) B1[tid] = b1[tid];
    if (tid < 32) B2[tid] = b2[tid];
    __syncthreads();

    const size_t row = (size_t)blockIdx.x*256 + tid;
    const float* xr = h2 + row*128;

    float hid[64];
    #pragma unroll
    for (int jj = 0; jj < 64; ++jj) hid[jj] = B1[jj];
    for (int k = 0; k < 64; k += 4) {
        float4 xv = *(const float4*)(xr + k);
        #pragma unroll
        for (int jj = 0; jj < 64; ++jj) {
            float s = hid[jj];
            s = fmaf(W1[jj*64 + k],     xv.x, s);
            s = fmaf(W1[jj*64 + k + 1], xv.y, s);
            s = fmaf(W1[jj*64 + k + 2], xv.z, s);
            s = fmaf(W1[jj*64 + k + 3], xv.w, s);
            hid[jj] = s;
        }
    }
    #pragma unroll
    for (int jj = 0; jj < 64; ++jj) hid[jj] = fmaxf(hid[jj], 0.f);

    float gm[16];
    #pragma unroll
    for (int jj = 0; jj < 16; ++jj) {
        float s = B2[jj];
        #pragma unroll
        for (int k = 0; k < 64; ++k) s = fmaf(W2[jj*64 + k], hid[k], s);
        gm[jj] = 100.f * tanh_f(0.001f * s);
    }
    float ge[16];
    #pragma unroll
    for (int d = 0; d < 16; d += 4) {
        float4 v = *(const float4*)(geps + row*16 + d);
        ge[d]=v.x; ge[d+1]=v.y; ge[d+2]=v.z; ge[d+3]=v.w;
    }
    float lsum = 0.f;
    float goalv[16];
    #pragma unroll
    for (int jj = 0; jj < 16; ++jj) {
        float s = B2[16 + jj];
        #pragma unroll
        for (int k = 0; k < 64; ++k) s = fmaf(W2[(16+jj)*64 + k], hid[k], s);
        float gs   = tanh_f(s);
        float gvar = fmaf(gs, gs, 0.001f);
        float goal = fmaf(sqrtf(gvar), ge[jj], gm[jj]);
        goalv[jj] = goal;
        float dd = goal - gm[jj];
        lsum += dd*dd/gvar + __logf(gvar);
    }
    #pragma unroll
    for (int d = 0; d < 16; d += 4) {
        float4 v = make_float4(goalv[d], goalv[d+1], goalv[d+2], goalv[d+3]);
        *(float4*)(out_goals + row*16 + d) = v;
    }
    out_lpg[row] = -0.5f*(lsum + 16.f*LOG2PI);
}

// ---------------------------------------------------------------------------
// Action + value decoder: goal_obs(80) -> [ad: 80 relu -> 16], [vd: 80 relu -> 1]
// ---------------------------------------------------------------------------
__global__ __launch_bounds__(256) void dec_av_kernel(
    const float* __restrict__ goals,
    const float* __restrict__ obs,
    const float* __restrict__ aeps,
    const float* __restrict__ aw1, const float* __restrict__ ab1,
    const float* __restrict__ aw2, const float* __restrict__ ab2,
    const float* __restrict__ vw1, const float* __restrict__ vb1,
    const float* __restrict__ vw2, const float* __restrict__ vb2,
    float* __restrict__ out_actions, float* __restrict__ out_lpa,
    float* __restrict__ out_values)
{
    __shared__ float AW1[80*80];
    __shared__ float VW1[80*80];
    __shared__ float AW2[16*80];
    __shared__ float VW2[80];
    __shared__ float AB1[80];
    __shared__ float VB1[80];
    __shared__ float AB2[16];
    const int tid = threadIdx.x;
    for (int e = tid; e < 80*80; e += 256) { AW1[e] = aw1[e]; VW1[e] = vw1[e]; }
    for (int e = tid; e < 16*80; e += 256) AW2[e] = aw2[e];
    if (tid < 80) { VW2[tid] = vw2[tid]; AB1[tid] = ab1[tid]; VB1[tid] = vb1[tid]; }
    if (tid < 16) AB2[tid] = ab2[tid];
    __syncthreads();

    const size_t row = (size_t)blockIdx.x*256 + tid;

    float hid[80];
    #pragma unroll
    for (int jj = 0; jj < 80; ++jj) hid[jj] = AB1[jj];
    for (int k = 0; k < 80; k += 4) {
        float4 xv;
        if (k < 16) xv = *(const float4*)(goals + row*16 + k);
        else        xv = *(const float4*)(obs + row*64 + (k - 16));
        #pragma unroll
        for (int jj = 0; jj < 80; ++jj) {
            float s = hid[jj];
            s = fmaf(AW1[jj*80 + k],     xv.x, s);
            s = fmaf(AW1[jj*80 + k + 1], xv.y, s);
            s = fmaf(AW1[jj*80 + k + 2], xv.z, s);
            s = fmaf(AW1[jj*80 + k + 3], xv.w, s);
            hid[jj] = s;
        }
    }
    #pragma unroll
    for (int jj = 0; jj < 80; ++jj) hid[jj] = fmaxf(hid[jj], 0.f);

    float am[8], asd[8];
    #pragma unroll
    for (int jj = 0; jj < 8; ++jj) {
        float s = AB2[jj];
        #pragma unroll
        for (int k = 0; k < 80; ++k) s = fmaf(AW2[jj*80 + k], hid[k], s);
        am[jj] = s;
    }
    #pragma unroll
    for (int jj = 0; jj < 8; ++jj) {
        float s = AB2[8 + jj];
        #pragma unroll
        for (int k = 0; k < 80; ++k) s = fmaf(AW2[(8+jj)*80 + k], hid[k], s);
        asd[jj] = s;
    }

    float ae[8];
    #pragma unroll
    for (int d = 0; d < 8; d += 4) {
        float4 v = *(const float4*)(aeps + row*8 + d);
        ae[d]=v.x; ae[d+1]=v.y; ae[d+2]=v.z; ae[d+3]=v.w;
    }
    float lsum = 0.f;
    float actv[8];
    #pragma unroll
    for (int d = 0; d < 8; ++d) {
        float avar = fmaf(asd[d], asd[d], 0.001f);
        float act  = fmaf(sqrtf(avar), ae[d], am[d]);
        actv[d] = act;
        float dd = act - am[d];
        lsum += dd*dd/avar + __logf(avar);
    }
    #pragma unroll
    for (int d = 0; d < 8; d += 4) {
        float4 v = make_float4(actv[d], actv[d+1], actv[d+2], actv[d+3]);
        *(float4*)(out_actions + row*8 + d) = v;
    }
    out_lpa[row] = -0.5f*(lsum + 8.f*LOG2PI);

    float vh[80];
    #pragma unroll
    for (int jj = 0; jj < 80; ++jj) vh[jj] = VB1[jj];
    for (int k = 0; k < 80; k += 4) {
        float4 xv;
        if (k < 16) xv = *(const float4*)(goals + row*16 + k);
        else        xv = *(const float4*)(obs + row*64 + (k - 16));
        #pragma unroll
        for (int jj = 0; jj < 80; ++jj) {
            float s = vh[jj];
            s = fmaf(VW1[jj*80 + k],     xv.x, s);
            s = fmaf(VW1[jj*80 + k + 1], xv.y, s);
            s = fmaf(VW1[jj*80 + k + 2], xv.z, s);
            s = fmaf(VW1[jj*80 + k + 3], xv.w, s);
            vh[jj] = s;
        }
    }
    float v = vb2[0];
    #pragma unroll
    for (int jj = 0; jj < 80; ++jj) v = fmaf(VW2[jj], fmaxf(vh[jj], 0.f), v);
    out_values[row] = v;
}

// ---------------------------------------------------------------------------
// lp decoder: full_lat_obs(192) -> 192 relu -> 1. 4 lanes per item,
// quad reduce via shfl_xor, w1 staged in LDS (float4) in 3 chunks of 64 rows.
// ---------------------------------------------------------------------------
__global__ __launch_bounds__(256) void dec_lpv_kernel(
    const float* __restrict__ h2,
    const float* __restrict__ obs,
    const float* __restrict__ w1, const float* __restrict__ b1,
    const float* __restrict__ w2, const float* __restrict__ b2,
    float* __restrict__ out_lpv)
{
    __shared__ __align__(16) float W1s[64*192];
    __shared__ float B1[192];
    __shared__ float W2[192];
    const int tid = threadIdx.x;
    const int l = tid & 3;
    const size_t item = (size_t)blockIdx.x*64 + (tid >> 2);
    if (tid < 192) { B1[tid] = b1[tid]; W2[tid] = w2[tid]; }

    float x[48];
    #pragma unroll
    for (int q = 0; q < 12; ++q) {
        int gk = l*48 + q*4;
        float4 v;
        if (gk < 128) v = *(const float4*)(h2 + item*128 + gk);
        else          v = *(const float4*)(obs + item*64 + (gk - 128));
        x[q*4]=v.x; x[q*4+1]=v.y; x[q*4+2]=v.z; x[q*4+3]=v.w;
    }

    float acc = 0.f;
    for (int j0 = 0; j0 < 192; j0 += 64) {
        __syncthreads();
        for (int e = tid; e < 64*48; e += 256) {
            int rr = e / 48, q = e - rr*48;
            *(float4*)&W1s[rr*192 + q*4] =
                *(const float4*)&w1[(size_t)(j0 + rr)*192 + q*4];
        }
        __syncthreads();
        for (int jj = 0; jj < 64; ++jj) {
            const float* wr = W1s + jj*192 + l*48;
            float p = 0.f;
            #pragma unroll
            for (int q = 0; q < 12; ++q) {
                float4 wv = *(const float4*)(wr + q*4);
                p = fmaf(wv.x, x[q*4],     p);
                p = fmaf(wv.y, x[q*4 + 1], p);
                p = fmaf(wv.z, x[q*4 + 2], p);
                p = fmaf(wv.w, x[q*4 + 3], p);
            }
            p += __shfl_xor(p, 1);
            p += __shfl_xor(p, 2);
            float h = fmaxf(p + B1[j0 + jj], 0.f);
            acc = fmaf(W2[j0 + jj], h, acc);
        }
    }
    if (l == 0) out_lpv[item] = acc + b2[0];
}

// ---------------------------------------------------------------------------
extern "C" void kernel_launch(void* const* d_in, const int* in_sizes, int n_in,
                              void* d_out, int out_size, void* d_ws, size_t ws_size,
                              hipStream_t stream)
{
    (void)in_sizes; (void)n_in; (void)out_size;

    const float* obs    = (const float*)d_in[0];
    const float* lps    = (const float*)d_in[1];
    const float* geps   = (const float*)d_in[2];
    const float* aeps   = (const float*)d_in[3];
    const float* h0     = (const float*)d_in[4];
    const float* c0     = (const float*)d_in[5];
    const float* w_ih0  = (const float*)d_in[6];
    const float* b_ih0  = (const float*)d_in[7];
    const float* w_hh0  = (const float*)d_in[8];
    const float* b_hh0  = (const float*)d_in[9];
    const float* w_ih1  = (const float*)d_in[10];
    const float* b_ih1  = (const float*)d_in[11];
    const float* w_hh1  = (const float*)d_in[12];
    const float* b_hh1  = (const float*)d_in[13];
    const float* gd_w1  = (const float*)d_in[14];
    const float* gd_b1  = (const float*)d_in[15];
    const float* gd_w2  = (const float*)d_in[16];
    const float* gd_b2  = (const float*)d_in[17];
    const float* ad_w1  = (const float*)d_in[18];
    const float* ad_b1  = (const float*)d_in[19];
    const float* ad_w2  = (const float*)d_in[20];
    const float* ad_b2  = (const float*)d_in[21];
    const float* vd_w1  = (const float*)d_in[22];
    const float* vd_b1  = (const float*)d_in[23];
    const float* vd_w2  = (const float*)d_in[24];
    const float* vd_b2  = (const float*)d_in[25];
    const float* lpd_w1 = (const float*)d_in[26];
    const float* lpd_b1 = (const float*)d_in[27];
    const float* lpd_w2 = (const float*)d_in[28];
    const float* lpd_b2 = (const float*)d_in[29];

    float* out         = (float*)d_out;
    float* out_actions = out;                 // (T,B,8)
    float* out_lpa     = out + 2097152;       // (T,B)
    float* out_goals   = out + 2359296;       // (T,B,16)
    float* out_lpg     = out + 6553600;       // (T,B)
    float* out_values  = out + 6815744;       // (T,B,1)
    float* out_lpv     = out + 7077888;       // (T,B,1)

    // --- adaptive time-chunking to fit ws_size ---
    const size_t STATE_ELEMS = 2ull * BB * 128;            // per h or c
    const size_t state_bytes = 2ull * STATE_ELEMS * 4;     // h + c
    int C = 0;
    for (int c = TT; c >= 8; c >>= 1) {
        size_t need = (size_t)c * BB * (512 + 128 + 128) * 4 + state_bytes;
        if (need <= ws_size) { C = c; break; }
    }
    if (C == 0) return;
    const int nchunks = TT / C;

    float* Gc      = (float*)d_ws;
    float* h1c     = Gc  + (size_t)C * BB * 512;
    float* h2c     = h1c + (size_t)C * BB * 128;
    float* h_state = h2c + (size_t)C * BB * 128;
    float* c_state = h_state + STATE_ELEMS;

    const dim3 blk(256);
    init_state_kernel<<<dim3((int)(STATE_ELEMS/256)), blk, 0, stream>>>(
        h0, c0, h_state, c_state);

    for (int ch = 0; ch < nchunks; ++ch) {
        const size_t crow0 = (size_t)ch * C * BB;
        const int rows = C * BB;

        gemm_ih_kernel<65, true><<<dim3((rows/64)*8), blk, 0, stream>>>(
            obs + crow0*64, lps + crow0, w_ih0, b_ih0, b_hh0, Gc);

        lstm_mfma_kernel<<<dim3(BB), dim3(512), 0, stream>>>(
            Gc, w_hh0, h_state, c_state, h1c, C);

        gemm_ih_kernel<128, false><<<dim3((rows/64)*8), blk, 0, stream>>>(
            h1c, nullptr, w_ih1, b_ih1, b_hh1, Gc);

        lstm_mfma_kernel<<<dim3(BB), dim3(512), 0, stream>>>(
            Gc, w_hh1, h_state + BB*128, c_state + BB*128, h2c, C);

        dec_goal_kernel<<<dim3(rows/256), blk, 0, stream>>>(
            h2c, geps + crow0*16, gd_w1, gd_b1, gd_w2, gd_b2,
            out_goals + crow0*16, out_lpg + crow0);

        dec_av_kernel<<<dim3(rows/256), blk, 0, stream>>>(
            out_goals + crow0*16, obs + crow0*64, aeps + crow0*8,
            ad_w1, ad_b1, ad_w2, ad_b2, vd_w1, vd_b1, vd_w2, vd_b2,
            out_actions + crow0*8, out_lpa + crow0, out_values + crow0);

        dec_lpv_kernel<<<dim3(rows/64), blk, 0, stream>>>(
            h2c, obs + crow0*64, lpd_w1, lpd_b1, lpd_w2, lpd_b2,
            out_lpv + crow0);
    }
}

// Round 9
// 3322.586 us; speedup vs baseline: 1.9201x; 1.0682x over previous
//
#include <hip/hip_runtime.h>
#include <hip/hip_bf16.h>
#include <math.h>

#define TT 1024
#define BB 256
#define LOG2PI 1.8378770664093453f

typedef short short8 __attribute__((ext_vector_type(8)));
typedef float f32x4  __attribute__((ext_vector_type(4)));

__device__ __forceinline__ float sigmoid_f(float x) {
    return 1.f / (1.f + __expf(-x));
}
__device__ __forceinline__ float tanh_f(float x) {
    return 1.f - 2.f / (__expf(2.f*x) + 1.f);
}
__device__ __forceinline__ unsigned short f2bf(float x) {   // RNE fp32->bf16
    unsigned int u = __float_as_uint(x);
    unsigned int r = (u + 0x7FFFu + ((u >> 16) & 1u)) >> 16;
    return (unsigned short)r;
}

// ---------------------------------------------------------------------------
// G[row][c] = X[row,:] . W[c,:] + bias1[c] + bias2[c]
// W is (512, K) row-major. 64-row x 64-col tile per 256-thread block.
// ---------------------------------------------------------------------------
template<int K, bool CONCAT>
__global__ __launch_bounds__(256) void gemm_ih_kernel(
    const float* __restrict__ Xa, const float* __restrict__ Xb,
    const float* __restrict__ W,
    const float* __restrict__ bias1, const float* __restrict__ bias2,
    float* __restrict__ Gout)
{
    __shared__ __align__(16) float Ws[64*68];
    __shared__ __align__(16) float Xs[64*68];
    const int tid   = threadIdx.x;
    const int chunk = blockIdx.x & 7;
    const int rtile = blockIdx.x >> 3;
    const int row0  = rtile * 64;
    const int c0    = chunk * 64;
    const int cgrp  = tid & 15;
    const int rgrp  = tid >> 4;

    float acc[4][4] = {};

    if constexpr (CONCAT) {
        for (int e = tid; e < 64*65; e += 256) {
            int c = e / 65, kk = e - c*65;
            Ws[c*68 + kk] = W[(size_t)(c0 + c)*65 + kk];
        }
        for (int e = tid; e < 64*65; e += 256) {
            int r = e / 65, kk = e - r*65;
            Xs[r*68 + kk] = (kk < 64) ? Xa[(size_t)(row0 + r)*64 + kk]
                                      : Xb[row0 + r];
        }
        __syncthreads();
        #pragma unroll 4
        for (int kq = 0; kq < 16; ++kq) {
            const int kk = kq*4;
            float4 xv[4], wv[4];
            #pragma unroll
            for (int rr = 0; rr < 4; ++rr)
                xv[rr] = *(const float4*)&Xs[(rgrp*4 + rr)*68 + kk];
            #pragma unroll
            for (int i = 0; i < 4; ++i)
                wv[i] = *(const float4*)&Ws[(cgrp + 16*i)*68 + kk];
            #pragma unroll
            for (int rr = 0; rr < 4; ++rr)
                #pragma unroll
                for (int i = 0; i < 4; ++i) {
                    float s = acc[rr][i];
                    s = fmaf(xv[rr].x, wv[i].x, s);
                    s = fmaf(xv[rr].y, wv[i].y, s);
                    s = fmaf(xv[rr].z, wv[i].z, s);
                    s = fmaf(xv[rr].w, wv[i].w, s);
                    acc[rr][i] = s;
                }
        }
        {
            float xv[4], wv[4];
            #pragma unroll
            for (int rr = 0; rr < 4; ++rr) xv[rr] = Xs[(rgrp*4 + rr)*68 + 64];
            #pragma unroll
            for (int i = 0; i < 4; ++i)  wv[i]  = Ws[(cgrp + 16*i)*68 + 64];
            #pragma unroll
            for (int rr = 0; rr < 4; ++rr)
                #pragma unroll
                for (int i = 0; i < 4; ++i)
                    acc[rr][i] = fmaf(xv[rr], wv[i], acc[rr][i]);
        }
    } else {
        for (int k0 = 0; k0 < K; k0 += 64) {
            for (int e = tid; e < 64*16; e += 256) {
                int c = e >> 4, q = e & 15;
                *(float4*)&Ws[c*68 + q*4] =
                    *(const float4*)&W[(size_t)(c0 + c)*K + k0 + q*4];
            }
            for (int e = tid; e < 64*16; e += 256) {
                int r = e >> 4, q = e & 15;
                *(float4*)&Xs[r*68 + q*4] =
                    *(const float4*)&Xa[(size_t)(row0 + r)*K + k0 + q*4];
            }
            __syncthreads();
            #pragma unroll 4
            for (int kq = 0; kq < 16; ++kq) {
                const int kk = kq*4;
                float4 xv[4], wv[4];
                #pragma unroll
                for (int rr = 0; rr < 4; ++rr)
                    xv[rr] = *(const float4*)&Xs[(rgrp*4 + rr)*68 + kk];
                #pragma unroll
                for (int i = 0; i < 4; ++i)
                    wv[i] = *(const float4*)&Ws[(cgrp + 16*i)*68 + kk];
                #pragma unroll
                for (int rr = 0; rr < 4; ++rr)
                    #pragma unroll
                    for (int i = 0; i < 4; ++i) {
                        float s = acc[rr][i];
                        s = fmaf(xv[rr].x, wv[i].x, s);
                        s = fmaf(xv[rr].y, wv[i].y, s);
                        s = fmaf(xv[rr].z, wv[i].z, s);
                        s = fmaf(xv[rr].w, wv[i].w, s);
                        acc[rr][i] = s;
                    }
            }
            __syncthreads();
        }
    }

    #pragma unroll
    for (int i = 0; i < 4; ++i) {
        const int c = c0 + cgrp + 16*i;
        const float bb = bias1[c] + bias2[c];
        #pragma unroll
        for (int rr = 0; rr < 4; ++rr) {
            const int r = row0 + rgrp*4 + rr;
            Gout[(size_t)r*512 + c] = acc[rr][i] + bb;
        }
    }
}

// ---------------------------------------------------------------------------
// MFMA sequential LSTM pass, one batch element per block (256 blocks).
// 512 threads = 8 waves. Tile tn = GATE BLOCK tn: j = tn*128 + wave*16 + col.
// A rows are broadcast-identical -> MFMA output is row-uniform -> every lane
// holds all 4 gate values for its column in a0[0],a1[0],a2[0],a3[0].
// kg==0 lanes (col = lane) do the whole nonlinearity + c/h update in-register.
// h double-buffered in LDS as bf16 -> ONE barrier/step (raw s_waitcnt
// lgkmcnt(0) + s_barrier + sched_barrier) so G loads (2-step prefetch) and
// h_all stores stay in flight across steps.
// BUGFIX r8->r9: capture g4 = GUSE BEFORE issuing the GRELOAD prefetch
// (r8 read the register after the prefetch clobbered it -> used G(t+2)).
// ---------------------------------------------------------------------------
__global__ __launch_bounds__(512, 2) void lstm_mfma_kernel(
    const float* __restrict__ G,       // (steps*BB, 512) chunk-local, incl. biases
    const float* __restrict__ wh,      // (512,128)
    float* __restrict__ h_state,       // (BB,128) in/out (layer slice)
    float* __restrict__ c_state,       // (BB,128) in/out
    float* __restrict__ h_all,         // (steps*BB,128) chunk-local
    int steps)
{
    const int tid  = threadIdx.x;
    const int wave = tid >> 6;          // 0..7
    const int lane = tid & 63;
    const int b    = blockIdx.x;
    const int col  = lane & 15;
    const int kg   = lane >> 4;         // k-group 0..3
    const int m    = wave*16 + col;     // h element owned by kg==0 lanes

    __shared__ __align__(16) unsigned short h_bf[2][128];  // double-buffered bf16 h

    // B fragments: tile tn = gate block tn; column n = col -> gate j = tn*128+m.
    short8 bfrag[4][4];   // [tile=gate block][kslice]
    {
        #pragma unroll
        for (int tn = 0; tn < 4; ++tn) {
            const int j = tn*128 + m;
            #pragma unroll
            for (int ks = 0; ks < 4; ++ks) {
                const float* src = wh + (size_t)j*128 + ks*32 + kg*8;
                short8 v;
                #pragma unroll
                for (int i = 0; i < 8; ++i) v[i] = (short)f2bf(src[i]);
                bfrag[tn][ks] = v;
            }
        }
    }

    float c_reg = 0.f, hv_last = 0.f;
    const size_t goff0 = (size_t)b*512 + m;   // i-gate offset; f/g/o at +128/+256/+384
    f32x4 gA = {0.f,0.f,0.f,0.f}, gB = gA;
    if (kg == 0) {
        hv_last = h_state[b*128 + m];
        c_reg   = c_state[b*128 + m];
        h_bf[0][m] = f2bf(hv_last);
        gA[0] = G[goff0];       gA[1] = G[goff0 + 128];
        gA[2] = G[goff0 + 256]; gA[3] = G[goff0 + 384];
        if (steps > 1) {
            const size_t o1 = (size_t)BB*512 + goff0;
            gB[0] = G[o1];       gB[1] = G[o1 + 128];
            gB[2] = G[o1 + 256]; gB[3] = G[o1 + 384];
        }
    }
    asm volatile("s_waitcnt lgkmcnt(0)" ::: "memory");
    __builtin_amdgcn_s_barrier();
    __builtin_amdgcn_sched_barrier(0);

    // One step: read h from buf RB, write new h to buf WB. Single barrier.
    #define LSTM_STEP(T_, GUSE, GRELOAD, TFAR, RB, WB)                          \
    {                                                                           \
        short8 af0 = *(const short8*)&h_bf[RB][0*32 + kg*8];                    \
        short8 af1 = *(const short8*)&h_bf[RB][1*32 + kg*8];                    \
        short8 af2 = *(const short8*)&h_bf[RB][2*32 + kg*8];                    \
        short8 af3 = *(const short8*)&h_bf[RB][3*32 + kg*8];                    \
        f32x4 g4 = (GUSE);              /* capture BEFORE prefetch clobbers */  \
        if (kg == 0 && (TFAR) < steps) {                                        \
            const size_t of = (size_t)(TFAR)*BB*512 + goff0;                    \
            f32x4 gg;                                                           \
            gg[0] = G[of];       gg[1] = G[of + 128];                           \
            gg[2] = G[of + 256]; gg[3] = G[of + 384];                           \
            (GRELOAD) = gg;                                                     \
        }                                                                       \
        f32x4 a0 = {0.f,0.f,0.f,0.f}, a1 = a0, a2 = a0, a3 = a0;                \
        a0 = __builtin_amdgcn_mfma_f32_16x16x32_bf16(af0, bfrag[0][0], a0,0,0,0);\
        a1 = __builtin_amdgcn_mfma_f32_16x16x32_bf16(af0, bfrag[1][0], a1,0,0,0);\
        a2 = __builtin_amdgcn_mfma_f32_16x16x32_bf16(af0, bfrag[2][0], a2,0,0,0);\
        a3 = __builtin_amdgcn_mfma_f32_16x16x32_bf16(af0, bfrag[3][0], a3,0,0,0);\
        a0 = __builtin_amdgcn_mfma_f32_16x16x32_bf16(af1, bfrag[0][1], a0,0,0,0);\
        a1 = __builtin_amdgcn_mfma_f32_16x16x32_bf16(af1, bfrag[1][1], a1,0,0,0);\
        a2 = __builtin_amdgcn_mfma_f32_16x16x32_bf16(af1, bfrag[2][1], a2,0,0,0);\
        a3 = __builtin_amdgcn_mfma_f32_16x16x32_bf16(af1, bfrag[3][1], a3,0,0,0);\
        a0 = __builtin_amdgcn_mfma_f32_16x16x32_bf16(af2, bfrag[0][2], a0,0,0,0);\
        a1 = __builtin_amdgcn_mfma_f32_16x16x32_bf16(af2, bfrag[1][2], a1,0,0,0);\
        a2 = __builtin_amdgcn_mfma_f32_16x16x32_bf16(af2, bfrag[2][2], a2,0,0,0);\
        a3 = __builtin_amdgcn_mfma_f32_16x16x32_bf16(af2, bfrag[3][2], a3,0,0,0);\
        a0 = __builtin_amdgcn_mfma_f32_16x16x32_bf16(af3, bfrag[0][3], a0,0,0,0);\
        a1 = __builtin_amdgcn_mfma_f32_16x16x32_bf16(af3, bfrag[1][3], a1,0,0,0);\
        a2 = __builtin_amdgcn_mfma_f32_16x16x32_bf16(af3, bfrag[2][3], a2,0,0,0);\
        a3 = __builtin_amdgcn_mfma_f32_16x16x32_bf16(af3, bfrag[3][3], a3,0,0,0);\
        if (kg == 0) {                                                          \
            float iv = sigmoid_f(a0[0] + g4[0]);                                \
            float fv = sigmoid_f(a1[0] + g4[1]);                                \
            float gv = tanh_f   (a2[0] + g4[2]);                                \
            float ov = sigmoid_f(a3[0] + g4[3]);                                \
            c_reg = fmaf(fv, c_reg, iv*gv);                                     \
            float hv = ov * tanh_f(c_reg);                                      \
            hv_last = hv;                                                       \
            h_bf[WB][m] = f2bf(hv);                                             \
            h_all[((size_t)(T_)*BB + b)*128 + m] = hv;                          \
        }                                                                       \
        asm volatile("s_waitcnt lgkmcnt(0)" ::: "memory");                      \
        __builtin_amdgcn_s_barrier();                                           \
        __builtin_amdgcn_sched_barrier(0);                                      \
    }

    for (int t = 0; t < steps; t += 2) {
        LSTM_STEP(t,     gA, gA, t + 2, 0, 1);
        LSTM_STEP(t + 1, gB, gB, t + 3, 1, 0);
    }
    #undef LSTM_STEP

    if (kg == 0) {
        h_state[b*128 + m] = hv_last;
        c_state[b*128 + m] = c_reg;
    }
}

// ---------------------------------------------------------------------------
__global__ __launch_bounds__(256) void init_state_kernel(
    const float* __restrict__ h0, const float* __restrict__ c0,
    float* __restrict__ h_state, float* __restrict__ c_state)
{
    const int idx = blockIdx.x*256 + threadIdx.x;
    h_state[idx] = h0[idx];
    c_state[idx] = c0[idx];
}

// ---------------------------------------------------------------------------
// Goal decoder: latents(64) -> 64 relu -> 32 ; goals + log_prob_goals
// ---------------------------------------------------------------------------
__global__ __launch_bounds__(256) void dec_goal_kernel(
    const float* __restrict__ h2,
    const float* __restrict__ geps,
    const float* __restrict__ w1, const float* __restrict__ b1,
    const float* __restrict__ w2, const float* __restrict__ b2,
    float* __restrict__ out_goals, float* __restrict__ out_lpg)
{
    __shared__ float W1[64*64];
    __shared__ float W2[32*64];
    __shared__ float B1[64];
    __shared__ float B2[32];
    const int tid = threadIdx.x;
    for (int e = tid; e < 64*64; e += 256) W1[e] = w1[e];
    for (int e = tid; e < 32*64; e += 256) W2[e] = w2[e];
    if (tid < 64) B1[tid] = b1[tid];
    if (tid < 32) B2[tid] = b2[tid];
    __syncthreads();

    const size_t row = (size_t)blockIdx.x*256 + tid;
    const float* xr = h2 + row*128;

    float hid[64];
    #pragma unroll
    for (int jj = 0; jj < 64; ++jj) hid[jj] = B1[jj];
    for (int k = 0; k < 64; k += 4) {
        float4 xv = *(const float4*)(xr + k);
        #pragma unroll
        for (int jj = 0; jj < 64; ++jj) {
            float s = hid[jj];
            s = fmaf(W1[jj*64 + k],     xv.x, s);
            s = fmaf(W1[jj*64 + k + 1], xv.y, s);
            s = fmaf(W1[jj*64 + k + 2], xv.z, s);
            s = fmaf(W1[jj*64 + k + 3], xv.w, s);
            hid[jj] = s;
        }
    }
    #pragma unroll
    for (int jj = 0; jj < 64; ++jj) hid[jj] = fmaxf(hid[jj], 0.f);

    float gm[16];
    #pragma unroll
    for (int jj = 0; jj < 16; ++jj) {
        float s = B2[jj];
        #pragma unroll
        for (int k = 0; k < 64; ++k) s = fmaf(W2[jj*64 + k], hid[k], s);
        gm[jj] = 100.f * tanh_f(0.001f * s);
    }
    float ge[16];
    #pragma unroll
    for (int d = 0; d < 16; d += 4) {
        float4 v = *(const float4*)(geps + row*16 + d);
        ge[d]=v.x; ge[d+1]=v.y; ge[d+2]=v.z; ge[d+3]=v.w;
    }
    float lsum = 0.f;
    float goalv[16];
    #pragma unroll
    for (int jj = 0; jj < 16; ++jj) {
        float s = B2[16 + jj];
        #pragma unroll
        for (int k = 0; k < 64; ++k) s = fmaf(W2[(16+jj)*64 + k], hid[k], s);
        float gs   = tanh_f(s);
        float gvar = fmaf(gs, gs, 0.001f);
        float goal = fmaf(sqrtf(gvar), ge[jj], gm[jj]);
        goalv[jj] = goal;
        float dd = goal - gm[jj];
        lsum += dd*dd/gvar + __logf(gvar);
    }
    #pragma unroll
    for (int d = 0; d < 16; d += 4) {
        float4 v = make_float4(goalv[d], goalv[d+1], goalv[d+2], goalv[d+3]);
        *(float4*)(out_goals + row*16 + d) = v;
    }
    out_lpg[row] = -0.5f*(lsum + 16.f*LOG2PI);
}

// ---------------------------------------------------------------------------
// Action + value decoder: goal_obs(80) -> [ad: 80 relu -> 16], [vd: 80 relu -> 1]
// ---------------------------------------------------------------------------
__global__ __launch_bounds__(256) void dec_av_kernel(
    const float* __restrict__ goals,
    const float* __restrict__ obs,
    const float* __restrict__ aeps,
    const float* __restrict__ aw1, const float* __restrict__ ab1,
    const float* __restrict__ aw2, const float* __restrict__ ab2,
    const float* __restrict__ vw1, const float* __restrict__ vb1,
    const float* __restrict__ vw2, const float* __restrict__ vb2,
    float* __restrict__ out_actions, float* __restrict__ out_lpa,
    float* __restrict__ out_values)
{
    __shared__ float AW1[80*80];
    __shared__ float VW1[80*80];
    __shared__ float AW2[16*80];
    __shared__ float VW2[80];
    __shared__ float AB1[80];
    __shared__ float VB1[80];
    __shared__ float AB2[16];
    const int tid = threadIdx.x;
    for (int e = tid; e < 80*80; e += 256) { AW1[e] = aw1[e]; VW1[e] = vw1[e]; }
    for (int e = tid; e < 16*80; e += 256) AW2[e] = aw2[e];
    if (tid < 80) { VW2[tid] = vw2[tid]; AB1[tid] = ab1[tid]; VB1[tid] = vb1[tid]; }
    if (tid < 16) AB2[tid] = ab2[tid];
    __syncthreads();

    const size_t row = (size_t)blockIdx.x*256 + tid;

    float hid[80];
    #pragma unroll
    for (int jj = 0; jj < 80; ++jj) hid[jj] = AB1[jj];
    for (int k = 0; k < 80; k += 4) {
        float4 xv;
        if (k < 16) xv = *(const float4*)(goals + row*16 + k);
        else        xv = *(const float4*)(obs + row*64 + (k - 16));
        #pragma unroll
        for (int jj = 0; jj < 80; ++jj) {
            float s = hid[jj];
            s = fmaf(AW1[jj*80 + k],     xv.x, s);
            s = fmaf(AW1[jj*80 + k + 1], xv.y, s);
            s = fmaf(AW1[jj*80 + k + 2], xv.z, s);
            s = fmaf(AW1[jj*80 + k + 3], xv.w, s);
            hid[jj] = s;
        }
    }
    #pragma unroll
    for (int jj = 0; jj < 80; ++jj) hid[jj] = fmaxf(hid[jj], 0.f);

    float am[8], asd[8];
    #pragma unroll
    for (int jj = 0; jj < 8; ++jj) {
        float s = AB2[jj];
        #pragma unroll
        for (int k = 0; k < 80; ++k) s = fmaf(AW2[jj*80 + k], hid[k], s);
        am[jj] = s;
    }
    #pragma unroll
    for (int jj = 0; jj < 8; ++jj) {
        float s = AB2[8 + jj];
        #pragma unroll
        for (int k = 0; k < 80; ++k) s = fmaf(AW2[(8+jj)*80 + k], hid[k], s);
        asd[jj] = s;
    }

    float ae[8];
    #pragma unroll
    for (int d = 0; d < 8; d += 4) {
        float4 v = *(const float4*)(aeps + row*8 + d);
        ae[d]=v.x; ae[d+1]=v.y; ae[d+2]=v.z; ae[d+3]=v.w;
    }
    float lsum = 0.f;
    float actv[8];
    #pragma unroll
    for (int d = 0; d < 8; ++d) {
        float avar = fmaf(asd[d], asd[d], 0.001f);
        float act  = fmaf(sqrtf(avar), ae[d], am[d]);
        actv[d] = act;
        float dd = act - am[d];
        lsum += dd*dd/avar + __logf(avar);
    }
    #pragma unroll
    for (int d = 0; d < 8; d += 4) {
        float4 v = make_float4(actv[d], actv[d+1], actv[d+2], actv[d+3]);
        *(float4*)(out_actions + row*8 + d) = v;
    }
    out_lpa[row] = -0.5f*(lsum + 8.f*LOG2PI);

    float vh[80];
    #pragma unroll
    for (int jj = 0; jj < 80; ++jj) vh[jj] = VB1[jj];
    for (int k = 0; k < 80; k += 4) {
        float4 xv;
        if (k < 16) xv = *(const float4*)(goals + row*16 + k);
        else        xv = *(const float4*)(obs + row*64 + (k - 16));
        #pragma unroll
        for (int jj = 0; jj < 80; ++jj) {
            float s = vh[jj];
            s = fmaf(VW1[jj*80 + k],     xv.x, s);
            s = fmaf(VW1[jj*80 + k + 1], xv.y, s);
            s = fmaf(VW1[jj*80 + k + 2], xv.z, s);
            s = fmaf(VW1[jj*80 + k + 3], xv.w, s);
            vh[jj] = s;
        }
    }
    float v = vb2[0];
    #pragma unroll
    for (int jj = 0; jj < 80; ++jj) v = fmaf(VW2[jj], fmaxf(vh[jj], 0.f), v);
    out_values[row] = v;
}

// ---------------------------------------------------------------------------
// lp decoder: full_lat_obs(192) -> 192 relu -> 1. 4 lanes per item,
// quad reduce via shfl_xor, w1 staged in LDS (float4) in 3 chunks of 64 rows.
// ---------------------------------------------------------------------------
__global__ __launch_bounds__(256) void dec_lpv_kernel(
    const float* __restrict__ h2,
    const float* __restrict__ obs,
    const float* __restrict__ w1, const float* __restrict__ b1,
    const float* __restrict__ w2, const float* __restrict__ b2,
    float* __restrict__ out_lpv)
{
    __shared__ __align__(16) float W1s[64*192];
    __shared__ float B1[192];
    __shared__ float W2[192];
    const int tid = threadIdx.x;
    const int l = tid & 3;
    const size_t item = (size_t)blockIdx.x*64 + (tid >> 2);
    if (tid < 192) { B1[tid] = b1[tid]; W2[tid] = w2[tid]; }

    float x[48];
    #pragma unroll
    for (int q = 0; q < 12; ++q) {
        int gk = l*48 + q*4;
        float4 v;
        if (gk < 128) v = *(const float4*)(h2 + item*128 + gk);
        else          v = *(const float4*)(obs + item*64 + (gk - 128));
        x[q*4]=v.x; x[q*4+1]=v.y; x[q*4+2]=v.z; x[q*4+3]=v.w;
    }

    float acc = 0.f;
    for (int j0 = 0; j0 < 192; j0 += 64) {
        __syncthreads();
        for (int e = tid; e < 64*48; e += 256) {
            int rr = e / 48, q = e - rr*48;
            *(float4*)&W1s[rr*192 + q*4] =
                *(const float4*)&w1[(size_t)(j0 + rr)*192 + q*4];
        }
        __syncthreads();
        for (int jj = 0; jj < 64; ++jj) {
            const float* wr = W1s + jj*192 + l*48;
            float p = 0.f;
            #pragma unroll
            for (int q = 0; q < 12; ++q) {
                float4 wv = *(const float4*)(wr + q*4);
                p = fmaf(wv.x, x[q*4],     p);
                p = fmaf(wv.y, x[q*4 + 1], p);
                p = fmaf(wv.z, x[q*4 + 2], p);
                p = fmaf(wv.w, x[q*4 + 3], p);
            }
            p += __shfl_xor(p, 1);
            p += __shfl_xor(p, 2);
            float h = fmaxf(p + B1[j0 + jj], 0.f);
            acc = fmaf(W2[j0 + jj], h, acc);
        }
    }
    if (l == 0) out_lpv[item] = acc + b2[0];
}

// ---------------------------------------------------------------------------
extern "C" void kernel_launch(void* const* d_in, const int* in_sizes, int n_in,
                              void* d_out, int out_size, void* d_ws, size_t ws_size,
                              hipStream_t stream)
{
    (void)in_sizes; (void)n_in; (void)out_size;

    const float* obs    = (const float*)d_in[0];
    const float* lps    = (const float*)d_in[1];
    const float* geps   = (const float*)d_in[2];
    const float* aeps   = (const float*)d_in[3];
    const float* h0     = (const float*)d_in[4];
    const float* c0     = (const float*)d_in[5];
    const float* w_ih0  = (const float*)d_in[6];
    const float* b_ih0  = (const float*)d_in[7];
    const float* w_hh0  = (const float*)d_in[8];
    const float* b_hh0  = (const float*)d_in[9];
    const float* w_ih1  = (const float*)d_in[10];
    const float* b_ih1  = (const float*)d_in[11];
    const float* w_hh1  = (const float*)d_in[12];
    const float* b_hh1  = (const float*)d_in[13];
    const float* gd_w1  = (const float*)d_in[14];
    const float* gd_b1  = (const float*)d_in[15];
    const float* gd_w2  = (const float*)d_in[16];
    const float* gd_b2  = (const float*)d_in[17];
    const float* ad_w1  = (const float*)d_in[18];
    const float* ad_b1  = (const float*)d_in[19];
    const float* ad_w2  = (const float*)d_in[20];
    const float* ad_b2  = (const float*)d_in[21];
    const float* vd_w1  = (const float*)d_in[22];
    const float* vd_b1  = (const float*)d_in[23];
    const float* vd_w2  = (const float*)d_in[24];
    const float* vd_b2  = (const float*)d_in[25];
    const float* lpd_w1 = (const float*)d_in[26];
    const float* lpd_b1 = (const float*)d_in[27];
    const float* lpd_w2 = (const float*)d_in[28];
    const float* lpd_b2 = (const float*)d_in[29];

    float* out         = (float*)d_out;
    float* out_actions = out;                 // (T,B,8)
    float* out_lpa     = out + 2097152;       // (T,B)
    float* out_goals   = out + 2359296;       // (T,B,16)
    float* out_lpg     = out + 6553600;       // (T,B)
    float* out_values  = out + 6815744;       // (T,B,1)
    float* out_lpv     = out + 7077888;       // (T,B,1)

    // --- adaptive time-chunking to fit ws_size ---
    const size_t STATE_ELEMS = 2ull * BB * 128;            // per h or c
    const size_t state_bytes = 2ull * STATE_ELEMS * 4;     // h + c
    int C = 0;
    for (int c = TT; c >= 8; c >>= 1) {
        size_t need = (size_t)c * BB * (512 + 128 + 128) * 4 + state_bytes;
        if (need <= ws_size) { C = c; break; }
    }
    if (C == 0) return;
    const int nchunks = TT / C;

    float* Gc      = (float*)d_ws;
    float* h1c     = Gc  + (size_t)C * BB * 512;
    float* h2c     = h1c + (size_t)C * BB * 128;
    float* h_state = h2c + (size_t)C * BB * 128;
    float* c_state = h_state + STATE_ELEMS;

    const dim3 blk(256);
    init_state_kernel<<<dim3((int)(STATE_ELEMS/256)), blk, 0, stream>>>(
        h0, c0, h_state, c_state);

    for (int ch = 0; ch < nchunks; ++ch) {
        const size_t crow0 = (size_t)ch * C * BB;
        const int rows = C * BB;

        gemm_ih_kernel<65, true><<<dim3((rows/64)*8), blk, 0, stream>>>(
            obs + crow0*64, lps + crow0, w_ih0, b_ih0, b_hh0, Gc);

        lstm_mfma_kernel<<<dim3(BB), dim3(512), 0, stream>>>(
            Gc, w_hh0, h_state, c_state, h1c, C);

        gemm_ih_kernel<128, false><<<dim3((rows/64)*8), blk, 0, stream>>>(
            h1c, nullptr, w_ih1, b_ih1, b_hh1, Gc);

        lstm_mfma_kernel<<<dim3(BB), dim3(512), 0, stream>>>(
            Gc, w_hh1, h_state + BB*128, c_state + BB*128, h2c, C);

        dec_goal_kernel<<<dim3(rows/256), blk, 0, stream>>>(
            h2c, geps + crow0*16, gd_w1, gd_b1, gd_w2, gd_b2,
            out_goals + crow0*16, out_lpg + crow0);

        dec_av_kernel<<<dim3(rows/256), blk, 0, stream>>>(
            out_goals + crow0*16, obs + crow0*64, aeps + crow0*8,
            ad_w1, ad_b1, ad_w2, ad_b2, vd_w1, vd_b1, vd_w2, vd_b2,
            out_actions + crow0*8, out_lpa + crow0, out_values + crow0);

        dec_lpv_kernel<<<dim3(rows/64), blk, 0, stream>>>(
            h2c, obs + crow0*64, lpd_w1, lpd_b1, lpd_w2, lpd_b2,
            out_lpv + crow0);
    }
}